// Round 21
// baseline (626.078 us; speedup 1.0000x reference)
//
#include <hip/hip_runtime.h>
#include <math.h>

#define NN 8000
#define NE 40000
#define NGB 256
#define SK 8192
#define KSPLIT 16

typedef unsigned int u32;
typedef unsigned short u16;
typedef __attribute__((ext_vector_type(8))) short short8v;
typedef __attribute__((ext_vector_type(4))) float float4v;
typedef __attribute__((ext_vector_type(4))) unsigned int uint4v;

__device__ __forceinline__ float sigmoidf_(float x) { return 1.f / (1.f + expf(-x)); }

__device__ __forceinline__ u32 bf16_rne(float f) {
    u32 x = __builtin_bit_cast(u32, f);
    return (x + 0x7FFFu + ((x >> 16) & 1u)) >> 16;
}

// pack 8 floats -> 8 bf16 (RNE) in a uint4
__device__ __forceinline__ uint4v pack_bf8(const float v[8]) {
    u32 h[8];
#pragma unroll
    for (int j = 0; j < 8; ++j) h[j] = bf16_rne(v[j]);
    return (uint4v){ h[0] | (h[1] << 16), h[2] | (h[3] << 16),
                     h[4] | (h[5] << 16), h[6] | (h[7] << 16) };
}

// load 8 consecutive floats, scale, split into hi/lo bf16x8 fragments (for tiny GEMMs)
__device__ __forceinline__ void pack8(const float* p, float scale, short8v& ah, short8v& al) {
    float v[8];
#pragma unroll
    for (int j = 0; j < 8; ++j) v[j] = p[j];
    u32 hu[8], lu[8];
#pragma unroll
    for (int j = 0; j < 8; ++j) {
        float s = v[j] * scale;
        hu[j] = bf16_rne(s);
        float fh = __builtin_bit_cast(float, hu[j] << 16);
        lu[j] = bf16_rne(s - fh);
    }
    uint4v hset = { hu[0] | (hu[1] << 16), hu[2] | (hu[3] << 16),
                    hu[4] | (hu[5] << 16), hu[6] | (hu[7] << 16) };
    uint4v lset = { lu[0] | (lu[1] << 16), lu[2] | (lu[3] << 16),
                    lu[4] | (lu[5] << 16), lu[6] | (lu[7] << 16) };
    ah = __builtin_bit_cast(short8v, hset);
    al = __builtin_bit_cast(short8v, lset);
}

// ---------- dedicated e_h kernel: LDS-staged w1, broadcast reads, vector ld/st ----------
__global__ __launch_bounds__(256) void k_eh(
    const float* __restrict__ ea, const float* __restrict__ w1,
    const float* __restrict__ b1, float* __restrict__ e_h) {
    __shared__ float w1s[2048];
    __shared__ float b1s[128];
    int t = threadIdx.x;
#pragma unroll
    for (int i = 0; i < 8; ++i) w1s[i * 256 + t] = w1[i * 256 + t];
    if (t < 128) b1s[t] = b1[t];
    __syncthreads();
    int e = blockIdx.x * 32 + (t & 31);
    int j0 = (t >> 5) * 16;
    const float4* ea4 = (const float4*)ea;
    float4 a0 = ea4[(size_t)e * 4 + 0], a1 = ea4[(size_t)e * 4 + 1];
    float4 a2 = ea4[(size_t)e * 4 + 2], a3 = ea4[(size_t)e * 4 + 3];
    float av[16] = {a0.x, a0.y, a0.z, a0.w, a1.x, a1.y, a1.z, a1.w,
                    a2.x, a2.y, a2.z, a2.w, a3.x, a3.y, a3.z, a3.w};
    float res[16];
#pragma unroll
    for (int jj = 0; jj < 16; ++jj) {
        int j = j0 + jj;
        float s = b1s[j];
#pragma unroll
        for (int c = 0; c < 16; ++c) s += av[c] * w1s[j * 16 + c];
        res[jj] = fmaxf(s, 0.f);
    }
    float4* op = (float4*)&e_h[(size_t)e * 128 + j0];
#pragma unroll
    for (int q = 0; q < 4; ++q)
        op[q] = make_float4(res[q * 4], res[q * 4 + 1], res[q * 4 + 2], res[q * 4 + 3]);
}

// ---------- fused setup: lin0 + wprep + gstart + degi-zero ----------
#define SETUP_LIN0 (NN * 64)
#define SETUP_W2   (64 * SK)
#define SETUP_MW   8192
#define SETUP_GB   24576
#define SETUP_G    (NGB + 1)
#define SETUP_TOTAL (SETUP_LIN0 + SETUP_W2 + SETUP_MW + SETUP_GB + SETUP_G + NN)
__global__ void k_setup(const float* __restrict__ x, const float* __restrict__ lin0_w,
                        const float* __restrict__ lin0_b,
                        const float* __restrict__ nn_w2, const float* __restrict__ conv_root,
                        const float* __restrict__ nn_b2, const float* __restrict__ gw_ih,
                        const float* __restrict__ gw_hh, const int* __restrict__ batch,
                        float* __restrict__ out,
                        u16* __restrict__ Whi, u16* __restrict__ Wlo,
                        u16* __restrict__ Bmh, u16* __restrict__ Bml,
                        u16* __restrict__ Bih_h, u16* __restrict__ Bih_l,
                        u16* __restrict__ Bhh_h, u16* __restrict__ Bhh_l,
                        int* __restrict__ gstart, int* __restrict__ degi) {
    int idx = blockIdx.x * 256 + threadIdx.x;
    if (idx < SETUP_LIN0) {
        int n = idx >> 6, o = idx & 63;
        float s = lin0_b[o];
#pragma unroll
        for (int c = 0; c < 21; ++c) s += x[n * 21 + c] * lin0_w[o * 21 + c];
        out[idx] = fmaxf(s, 0.f);
        return;
    }
    idx -= SETUP_LIN0;
    if (idx < SETUP_W2) {
        int o = idx >> 13, kap = idx & 8191;
        int i = kap >> 7, k = kap & 127;
        float v = nn_w2[(size_t)((i << 6) + o) * 128 + k];
        u32 h = bf16_rne(v);
        float fh = __builtin_bit_cast(float, h << 16);
        u32 l = bf16_rne(v - fh);
        int pos = ((kap >> 3) * 64 + o) * 8 + (kap & 7);
        Whi[pos] = (u16)h; Wlo[pos] = (u16)l;
        return;
    }
    idx -= SETUP_W2;
    if (idx < SETUP_MW) {
        int k = idx >> 6, o = idx & 63;
        float v = (k < 64) ? nn_b2[k * 64 + o] : conv_root[(k - 64) * 64 + o];
        u32 h = bf16_rne(v);
        float fh = __builtin_bit_cast(float, h << 16);
        u32 l = bf16_rne(v - fh);
        int pos = ((k >> 3) * 64 + o) * 8 + (k & 7);
        Bmh[pos] = (u16)h; Bml[pos] = (u16)l;
        return;
    }
    idx -= SETUP_MW;
    if (idx < SETUP_GB) {
        int half = idx >= 12288;
        int i2 = idx - half * 12288;
        int o = i2 % 192, k = i2 / 192;
        float v = half ? gw_hh[o * 64 + k] : gw_ih[o * 64 + k];
        u32 h = bf16_rne(v);
        float fh = __builtin_bit_cast(float, h << 16);
        u32 l = bf16_rne(v - fh);
        int pos = ((k >> 3) * 192 + o) * 8 + (k & 7);
        if (half) { Bhh_h[pos] = (u16)h; Bhh_l[pos] = (u16)l; }
        else      { Bih_h[pos] = (u16)h; Bih_l[pos] = (u16)l; }
        return;
    }
    idx -= SETUP_GB;
    if (idx < SETUP_G) {
        int g = idx;
        int lo = 0, hi = NN;
        while (lo < hi) { int mid = (lo + hi) >> 1; if (batch[mid] < g) lo = mid + 1; else hi = mid; }
        gstart[g] = lo;
        return;
    }
    idx -= SETUP_G;
    if (idx < NN) degi[idx] = 0;
}

__global__ void k_deg(const int* __restrict__ dst, int* __restrict__ degi) {
    int e = blockIdx.x * blockDim.x + threadIdx.x;
    if (e < NE) atomicAdd(&degi[dst[e]], 1);
}

// single-block scan, sequential 8-per-thread chunks + one LDS log-scan
__global__ __launch_bounds__(1024) void k_scan(
    const int* __restrict__ degi, int* __restrict__ rowptr,
    int* __restrict__ cursor, float* __restrict__ degf) {
    __shared__ int tsum[1024];
    int t = threadIdx.x;
    int base = t * 8;
    int v[8];
    int s = 0;
#pragma unroll
    for (int j = 0; j < 8; ++j) {
        int i = base + j;
        v[j] = (i < NN) ? degi[i] : 0;
        s += v[j];
    }
    tsum[t] = s;
    __syncthreads();
    for (int off = 1; off < 1024; off <<= 1) {
        int add = (t >= off) ? tsum[t - off] : 0;
        __syncthreads();
        tsum[t] += add;
        __syncthreads();
    }
    int exc = (t == 0) ? 0 : tsum[t - 1];
#pragma unroll
    for (int j = 0; j < 8; ++j) {
        int i = base + j;
        if (i < NN) {
            rowptr[i] = exc; cursor[i] = exc;
            degf[i] = (float)(v[j] > 1 ? v[j] : 1);
            exc += v[j];
        }
    }
    if (t == 1023) rowptr[NN] = tsum[1023];
}

__global__ void k_fill(const int* __restrict__ dst, int* __restrict__ cursor,
                       int* __restrict__ elist) {
    int e = blockIdx.x * blockDim.x + threadIdx.x;
    if (e < NE) { int p = atomicAdd(&cursor[dst[e]], 1); elist[p] = e; }
}

// ---------- NNConv: S build (bf16 S) ----------
__global__ __launch_bounds__(256) void k_sbuild(
    const float* __restrict__ out, const float* __restrict__ e_h,
    const int* __restrict__ src, const int* __restrict__ rowptr,
    const int* __restrict__ elist, u16* __restrict__ S_bf,
    float* __restrict__ Osum, int base) {
    int t = threadIdx.x;
    int n = base + blockIdx.x;
    int ig = t >> 4;
    int k8 = t & 15;
    int lane = t & 63;
    float acc[4][8];
#pragma unroll
    for (int j = 0; j < 4; ++j)
#pragma unroll
        for (int c = 0; c < 8; ++c) acc[j][c] = 0.f;
    float osum = 0.f;
    int r0 = rowptr[n], r1 = rowptr[n + 1];
    const float4* out4 = (const float4*)out;
    const float4* eh4p = (const float4*)e_h;
    for (int idx = r0; idx < r1; ++idx) {
        int e = elist[idx];
        int sn = src[e];
        float4 e0 = eh4p[(size_t)e * 32 + k8 * 2];
        float4 e1 = eh4p[(size_t)e * 32 + k8 * 2 + 1];
        float ehv[8] = {e0.x, e0.y, e0.z, e0.w, e1.x, e1.y, e1.z, e1.w};
        float4 f = out4[sn * 16 + ig];
        float fv[4] = {f.x, f.y, f.z, f.w};
#pragma unroll
        for (int j = 0; j < 4; ++j)
#pragma unroll
            for (int c = 0; c < 8; ++c) acc[j][c] += fv[j] * ehv[c];
        if (t < 64) osum += out[(size_t)sn * 64 + lane];
    }
    uint4v* S4 = (uint4v*)S_bf;
    size_t rb = (size_t)blockIdx.x * (SK / 8);
#pragma unroll
    for (int j = 0; j < 4; ++j)
        S4[rb + (size_t)(ig * 4 + j) * 16 + k8] = pack_bf8(acc[j]);
    if (t < 64) Osum[(size_t)n * 64 + lane] = osum;
}

// ---------- NNConv: MFMA GEMM. 1 wave/block, M=32/wave, A-strip hoisted, bf16 P ----------
__global__ __launch_bounds__(64, 2) void k_gemm(
    const u16* __restrict__ S_bf, const u16* __restrict__ Whi,
    const u16* __restrict__ Wlo, u16* __restrict__ P, int base) {
    int lane = threadIdx.x;
    int lrow = lane & 15, lkg = lane >> 4;
    int m0 = blockIdx.x * 32;
    int ks = blockIdx.y;
    int kbase = ks * (SK / KSPLIT);         // 512 kappa per split
    float4v acc[2][4];
#pragma unroll
    for (int ms = 0; ms < 2; ++ms)
#pragma unroll
        for (int nt = 0; nt < 4; ++nt) acc[ms][nt] = (float4v){0.f, 0.f, 0.f, 0.f};
    const short8v* bhv = (const short8v*)Whi;
    const short8v* blv = (const short8v*)Wlo;
    const u16* ar0 = S_bf + (size_t)(m0 + lrow) * SK + kbase + lkg * 8;
    const u16* ar1 = ar0 + (size_t)16 * SK;
    int kc0 = (kbase >> 3) + lkg;

    // hoist full A strips into registers (32 x 16B = 512 B/lane) — one burst of
    // independent loads so the memory system sees maximal outstanding bytes
    short8v a0s[16], a1s[16];
#pragma unroll
    for (int kk = 0; kk < 16; ++kk) {
        a0s[kk] = *(const short8v*)(ar0 + kk * 32);
        a1s[kk] = *(const short8v*)(ar1 + kk * 32);
    }
#pragma unroll 4
    for (int kk = 0; kk < 16; ++kk) {
        int bo = (kc0 + kk * 4) * 64 + lrow;
        short8v bh[4], bl[4];
#pragma unroll
        for (int nt = 0; nt < 4; ++nt) { bh[nt] = bhv[bo + nt * 16]; bl[nt] = blv[bo + nt * 16]; }
#pragma unroll
        for (int nt = 0; nt < 4; ++nt) {
            acc[0][nt] = __builtin_amdgcn_mfma_f32_16x16x32_bf16(a0s[kk], bh[nt], acc[0][nt], 0, 0, 0);
            acc[0][nt] = __builtin_amdgcn_mfma_f32_16x16x32_bf16(a0s[kk], bl[nt], acc[0][nt], 0, 0, 0);
            acc[1][nt] = __builtin_amdgcn_mfma_f32_16x16x32_bf16(a1s[kk], bh[nt], acc[1][nt], 0, 0, 0);
            acc[1][nt] = __builtin_amdgcn_mfma_f32_16x16x32_bf16(a1s[kk], bl[nt], acc[1][nt], 0, 0, 0);
        }
    }
    int gbase = base + m0;
#pragma unroll
    for (int ms = 0; ms < 2; ++ms)
#pragma unroll
        for (int nt = 0; nt < 4; ++nt)
#pragma unroll
            for (int jj = 0; jj < 4; ++jj) {
                int row = ms * 16 + lkg * 4 + jj;   // C/D: row=(lane>>4)*4+reg  [m89 verified]
                int o = nt * 16 + lrow;             //      col=lane&15
                P[((size_t)ks * NN + gbase + row) * 64 + o] = (u16)bf16_rne(acc[ms][nt][jj]);
            }
}

// ---------- fused node update: psum(bf16 P) + mrelu(MFMA) + GRU gates(MFMA) ----------
__global__ __launch_bounds__(64) void k_node(
    float* __restrict__ out, const u16* __restrict__ P,
    const float* __restrict__ Osum, const float* __restrict__ degf,
    const u16* __restrict__ Bmh, const u16* __restrict__ Bml,
    const u16* __restrict__ Bih_h, const u16* __restrict__ Bih_l,
    const u16* __restrict__ Bhh_h, const u16* __restrict__ Bhh_l,
    const float* __restrict__ conv_bias,
    const float* __restrict__ gb_ih, const float* __restrict__ gb_hh) {
    __shared__ float lds[16][68];     // psum, then M (padded stride 68)
    int lane = threadIdx.x;
    int lrow = lane & 15, lkg = lane >> 4;
    int n0 = blockIdx.x * 16;
    int arow = n0 + lrow;

    // phase 1: Psum[arow][lkg*16 .. +15] = sum over KSPLIT bf16 planes
    {
        float ps[16];
#pragma unroll
        for (int c = 0; c < 16; ++c) ps[c] = 0.f;
        for (int p = 0; p < KSPLIT; ++p) {
            const uint4v* Pp = (const uint4v*)(P + (size_t)p * (NN * 64) + (size_t)arow * 64 + lkg * 16);
            uint4v v0 = Pp[0], v1 = Pp[1];
            u32 wv[8] = {v0.x, v0.y, v0.z, v0.w, v1.x, v1.y, v1.z, v1.w};
#pragma unroll
            for (int q = 0; q < 8; ++q) {
                ps[q * 2]     += __builtin_bit_cast(float, wv[q] << 16);
                ps[q * 2 + 1] += __builtin_bit_cast(float, wv[q] & 0xFFFF0000u);
            }
        }
#pragma unroll
        for (int c = 0; c < 16; ++c) lds[lrow][lkg * 16 + c] = ps[c];
    }
    __syncthreads();

    // phase 2: mrelu MFMA (A rows: Osum/deg then out; B: nn_b2 then conv_root)
    float invd = 1.f / degf[arow];
    float4v acc[4];
#pragma unroll
    for (int nt = 0; nt < 4; ++nt) acc[nt] = (float4v){0.f, 0.f, 0.f, 0.f};
    const short8v* bhv = (const short8v*)Bmh;
    const short8v* blv = (const short8v*)Bml;
#pragma unroll
    for (int s = 0; s < 4; ++s) {
        short8v ah, al;
        if (s < 2) pack8(&Osum[(size_t)arow * 64 + s * 32 + lkg * 8], invd, ah, al);
        else       pack8(&out[(size_t)arow * 64 + (s - 2) * 32 + lkg * 8], 1.f, ah, al);
        int kc = s * 4 + lkg;
#pragma unroll
        for (int nt = 0; nt < 4; ++nt) {
            short8v bh = bhv[kc * 64 + nt * 16 + lrow];
            short8v bl = blv[kc * 64 + nt * 16 + lrow];
            acc[nt] = __builtin_amdgcn_mfma_f32_16x16x32_bf16(ah, bh, acc[nt], 0, 0, 0);
            acc[nt] = __builtin_amdgcn_mfma_f32_16x16x32_bf16(al, bh, acc[nt], 0, 0, 0);
            acc[nt] = __builtin_amdgcn_mfma_f32_16x16x32_bf16(ah, bl, acc[nt], 0, 0, 0);
        }
    }
    float invd2[4];
#pragma unroll
    for (int jj = 0; jj < 4; ++jj) invd2[jj] = 1.f / degf[n0 + lkg * 4 + jj];
    float mval[4][4];
#pragma unroll
    for (int nt = 0; nt < 4; ++nt) {
        int o = nt * 16 + lrow;
        float cb = conv_bias[o];
#pragma unroll
        for (int jj = 0; jj < 4; ++jj)
            mval[nt][jj] = fmaxf(acc[nt][jj] + lds[lkg * 4 + jj][o] * invd2[jj] + cb, 0.f);
    }
    __syncthreads();   // all psum reads done
#pragma unroll
    for (int nt = 0; nt < 4; ++nt)
#pragma unroll
        for (int jj = 0; jj < 4; ++jj)
            lds[lkg * 4 + jj][nt * 16 + lrow] = mval[nt][jj];
    __syncthreads();   // M ready in LDS

    // phase 3: GRU gates MFMA
    float4v ai[12], ah_[12];
#pragma unroll
    for (int nt = 0; nt < 12; ++nt) { ai[nt] = (float4v){0.f, 0.f, 0.f, 0.f}; ah_[nt] = (float4v){0.f, 0.f, 0.f, 0.f}; }
    const short8v* bih_h = (const short8v*)Bih_h;
    const short8v* bih_l = (const short8v*)Bih_l;
    const short8v* bhh_h = (const short8v*)Bhh_h;
    const short8v* bhh_l = (const short8v*)Bhh_l;
#pragma unroll
    for (int s = 0; s < 2; ++s) {
        short8v mh, ml, hh, hl;
        pack8(&lds[lrow][s * 32 + lkg * 8], 1.f, mh, ml);
        pack8(&out[(size_t)arow * 64 + s * 32 + lkg * 8], 1.f, hh, hl);
        int kc = s * 4 + lkg;
#pragma unroll
        for (int nt = 0; nt < 12; ++nt) {
            int bo = kc * 192 + nt * 16 + lrow;
            short8v b1 = bih_h[bo], b2 = bih_l[bo];
            ai[nt] = __builtin_amdgcn_mfma_f32_16x16x32_bf16(mh, b1, ai[nt], 0, 0, 0);
            ai[nt] = __builtin_amdgcn_mfma_f32_16x16x32_bf16(ml, b1, ai[nt], 0, 0, 0);
            ai[nt] = __builtin_amdgcn_mfma_f32_16x16x32_bf16(mh, b2, ai[nt], 0, 0, 0);
            short8v b3 = bhh_h[bo], b4 = bhh_l[bo];
            ah_[nt] = __builtin_amdgcn_mfma_f32_16x16x32_bf16(hh, b3, ah_[nt], 0, 0, 0);
            ah_[nt] = __builtin_amdgcn_mfma_f32_16x16x32_bf16(hl, b3, ah_[nt], 0, 0, 0);
            ah_[nt] = __builtin_amdgcn_mfma_f32_16x16x32_bf16(hh, b4, ah_[nt], 0, 0, 0);
        }
    }
#pragma unroll
    for (int nt = 0; nt < 4; ++nt) {
        int o = nt * 16 + lrow;
        float bi0 = gb_ih[o], bi1 = gb_ih[64 + o], bi2 = gb_ih[128 + o];
        float bh0 = gb_hh[o], bh1 = gb_hh[64 + o], bh2 = gb_hh[128 + o];
#pragma unroll
        for (int jj = 0; jj < 4; ++jj) {
            int row = n0 + lkg * 4 + jj;
            float ir = ai[nt][jj] + bi0,  hr = ah_[nt][jj] + bh0;
            float iz = ai[nt + 4][jj] + bi1, hz = ah_[nt + 4][jj] + bh1;
            float in_ = ai[nt + 8][jj] + bi2, hn = ah_[nt + 8][jj] + bh2;
            float r = sigmoidf_(ir + hr);
            float z = sigmoidf_(iz + hz);
            float nv = tanhf(in_ + r * hn);
            float ho = out[(size_t)row * 64 + o];
            out[(size_t)row * 64 + o] = (1.f - z) * nv + z * ho;
        }
    }
}

// ---------- fused Set2Set: 3x(LSTM+attention) + final linear, one block per graph ----------
__global__ __launch_bounds__(256) void k_s2s(
    const float* __restrict__ out, const int* __restrict__ gstart,
    const float* __restrict__ lw_ih, const float* __restrict__ lw_hh,
    const float* __restrict__ lb_ih, const float* __restrict__ lb_hh,
    const float* __restrict__ lin1_w, const float* __restrict__ lin1_b,
    const float* __restrict__ lin2_w, const float* __restrict__ lin2_b,
    float* __restrict__ yout) {
    __shared__ float qs[128], hsL[64], csL[64], gates[256];
    __shared__ float pv[384];
    __shared__ float red[4][64];
    __shared__ float sswv[4], mmaxw[4];
    int g = blockIdx.x, t = threadIdx.x, wv = t >> 6, lane = t & 63;
    int s0 = gstart[g], s1 = gstart[g + 1];
    if (t < 128) qs[t] = 0.f;
    if (t < 64) { hsL[t] = 0.f; csL[t] = 0.f; }
    __syncthreads();
    for (int st = 0; st < 3; ++st) {
        float s = lb_ih[t] + lb_hh[t];
        const float4* wi = (const float4*)&lw_ih[t * 128];
#pragma unroll
        for (int i = 0; i < 32; ++i) {
            float4 a = wi[i];
            s += qs[i * 4] * a.x + qs[i * 4 + 1] * a.y + qs[i * 4 + 2] * a.z + qs[i * 4 + 3] * a.w;
        }
        const float4* wh = (const float4*)&lw_hh[t * 64];
#pragma unroll
        for (int i = 0; i < 16; ++i) {
            float4 a = wh[i];
            s += hsL[i * 4] * a.x + hsL[i * 4 + 1] * a.y + hsL[i * 4 + 2] * a.z + hsL[i * 4 + 3] * a.w;
        }
        gates[t] = s;
        __syncthreads();
        if (t < 64) {
            float ig = sigmoidf_(gates[t]);
            float fg = sigmoidf_(gates[64 + t]);
            float gg = tanhf(gates[128 + t]);
            float og = sigmoidf_(gates[192 + t]);
            float c = fg * csL[t] + ig * gg;
            csL[t] = c;
            hsL[t] = og * tanhf(c);
        }
        __syncthreads();
        float wmax = -1e30f;
        for (int i = s0 + wv; i < s1; i += 4) {
            float p = out[(size_t)i * 64 + lane] * hsL[lane];
#pragma unroll
            for (int off = 32; off >= 1; off >>= 1) p += __shfl_xor(p, off);
            if (lane == 0) pv[i - s0] = p;
            wmax = fmaxf(wmax, p);
        }
        if (lane == 0) mmaxw[wv] = wmax;
        __syncthreads();
        float mmax = fmaxf(fmaxf(mmaxw[0], mmaxw[1]), fmaxf(mmaxw[2], mmaxw[3]));
        float ssum = 0.f, racc = 0.f;
        for (int i = s0 + wv; i < s1; i += 4) {
            float w = expf(pv[i - s0] - mmax);
            ssum += w;
            racc += w * out[(size_t)i * 64 + lane];
        }
        red[wv][lane] = racc;
        if (lane == 0) sswv[wv] = ssum;
        __syncthreads();
        if (t < 64) {
            float rt = red[0][t] + red[1][t] + red[2][t] + red[3][t];
            float stot = sswv[0] + sswv[1] + sswv[2] + sswv[3];
            qs[t] = hsL[t];
            qs[64 + t] = (s1 > s0) ? rt / stot : 0.f;
        }
        __syncthreads();
    }
    if (t < 64) {
        float s = lin1_b[t];
        const float4* w1 = (const float4*)&lin1_w[t * 128];
#pragma unroll
        for (int i = 0; i < 32; ++i) {
            float4 a = w1[i];
            s += qs[i * 4] * a.x + qs[i * 4 + 1] * a.y + qs[i * 4 + 2] * a.z + qs[i * 4 + 3] * a.w;
        }
        s = fmaxf(s, 0.f) * lin2_w[t];
#pragma unroll
        for (int off = 32; off >= 1; off >>= 1) s += __shfl_xor(s, off);
        if (t == 0) yout[g] = s + lin2_b[0];
    }
}

extern "C" void kernel_launch(void* const* d_in, const int* in_sizes, int n_in,
                              void* d_out, int out_size, void* d_ws, size_t ws_size,
                              hipStream_t stream) {
    (void)in_sizes; (void)n_in; (void)out_size;
    const float* x        = (const float*)d_in[0];
    const float* eattr    = (const float*)d_in[1];
    const int*   ei       = (const int*)d_in[2];
    const int*   batch    = (const int*)d_in[3];
    const float* lin0_w   = (const float*)d_in[4];
    const float* lin0_b   = (const float*)d_in[5];
    const float* nn_w1    = (const float*)d_in[6];
    const float* nn_b1    = (const float*)d_in[7];
    const float* nn_w2    = (const float*)d_in[8];
    const float* nn_b2    = (const float*)d_in[9];
    const float* conv_root= (const float*)d_in[10];
    const float* conv_bias= (const float*)d_in[11];
    const float* gw_ih    = (const float*)d_in[12];
    const float* gw_hh    = (const float*)d_in[13];
    const float* gb_ih    = (const float*)d_in[14];
    const float* gb_hh    = (const float*)d_in[15];
    const float* lw_ih    = (const float*)d_in[16];
    const float* lw_hh    = (const float*)d_in[17];
    const float* lb_ih    = (const float*)d_in[18];
    const float* lb_hh    = (const float*)d_in[19];
    const float* lin1_w   = (const float*)d_in[20];
    const float* lin1_b   = (const float*)d_in[21];
    const float* lin2_w   = (const float*)d_in[22];
    const float* lin2_b   = (const float*)d_in[23];
    const int* src = ei;
    const int* dst = ei + NE;

    char* w = (char*)d_ws;
    auto alloc = [&](size_t bytes) { char* p = w; w += (bytes + 255) & ~(size_t)255; return p; };
    float* out    = (float*)alloc((size_t)NN * 64 * 4);
    float* e_h    = (float*)alloc((size_t)NE * 128 * 4);
    u16*   Whi    = (u16*)alloc((size_t)64 * SK * 2);
    u16*   Wlo    = (u16*)alloc((size_t)64 * SK * 2);
    u16*   P      = (u16*)alloc((size_t)KSPLIT * NN * 64 * 2);
    float* Osum   = (float*)alloc((size_t)NN * 64 * 4);
    u16*   Bmh    = (u16*)alloc((size_t)8192 * 2);
    u16*   Bml    = (u16*)alloc((size_t)8192 * 2);
    u16*   Bih_h  = (u16*)alloc((size_t)12288 * 2);
    u16*   Bih_l  = (u16*)alloc((size_t)12288 * 2);
    u16*   Bhh_h  = (u16*)alloc((size_t)12288 * 2);
    u16*   Bhh_l  = (u16*)alloc((size_t)12288 * 2);
    float* degf   = (float*)alloc((size_t)NN * 4);
    int*   degi   = (int*)alloc((size_t)NN * 4);
    int*   rowptr = (int*)alloc((size_t)(NN + 1) * 4);
    int*   cursor = (int*)alloc((size_t)(NN + 1) * 4);
    int*   elist  = (int*)alloc((size_t)NE * 4);
    int*   gstart = (int*)alloc((size_t)(NGB + 1) * 4);
    size_t used = (size_t)(w - (char*)d_ws);
    size_t avail = ws_size > used ? ws_size - used : 0;
    size_t maxrows = avail / ((size_t)SK * 2);      // bf16 S: 16 KB per row
    int chunkN = maxrows > (size_t)NN ? NN : (int)maxrows;
    chunkN = (chunkN / 64) * 64;
    if (chunkN < 64) chunkN = 64;
    u16* S_bf = (u16*)w;

    k_setup<<<(SETUP_TOTAL + 255) / 256, 256, 0, stream>>>(
        x, lin0_w, lin0_b, nn_w2, conv_root, nn_b2,
        gw_ih, gw_hh, batch, out, Whi, Wlo, Bmh, Bml,
        Bih_h, Bih_l, Bhh_h, Bhh_l, gstart, degi);
    k_eh<<<NE / 32, 256, 0, stream>>>(eattr, nn_w1, nn_b1, e_h);
    k_deg<<<(NE + 255) / 256, 256, 0, stream>>>(dst, degi);
    k_scan<<<1, 1024, 0, stream>>>(degi, rowptr, cursor, degf);
    k_fill<<<(NE + 255) / 256, 256, 0, stream>>>(dst, cursor, elist);

    for (int it = 0; it < 3; ++it) {
        for (int cb = 0; cb < NN; cb += chunkN) {
            int cn = (NN - cb) < chunkN ? (NN - cb) : chunkN;
            k_sbuild<<<cn, 256, 0, stream>>>(out, e_h, src, rowptr, elist, S_bf, Osum, cb);
            k_gemm<<<dim3(cn / 32, KSPLIT), 64, 0, stream>>>(S_bf, Whi, Wlo, P, cb);
        }
        k_node<<<NN / 16, 64, 0, stream>>>(out, P, Osum, degf, Bmh, Bml,
                                           Bih_h, Bih_l, Bhh_h, Bhh_l,
                                           conv_bias, gb_ih, gb_hh);
    }

    k_s2s<<<NGB, 256, 0, stream>>>(out, gstart, lw_ih, lw_hh, lb_ih, lb_hh,
                                   lin1_w, lin1_b, lin2_w, lin2_b, (float*)d_out);
}

// Round 22
// 354.691 us; speedup vs baseline: 1.7651x; 1.7651x over previous
//
#include <hip/hip_runtime.h>
#include <math.h>

#define NN 8000
#define NE 40000
#define NGB 256
#define SK 8192
#define KSPLIT 16

typedef unsigned int u32;
typedef unsigned short u16;
typedef __attribute__((ext_vector_type(8))) short short8v;
typedef __attribute__((ext_vector_type(4))) float float4v;
typedef __attribute__((ext_vector_type(4))) unsigned int uint4v;

__device__ __forceinline__ float sigmoidf_(float x) { return 1.f / (1.f + expf(-x)); }

__device__ __forceinline__ u32 bf16_rne(float f) {
    u32 x = __builtin_bit_cast(u32, f);
    return (x + 0x7FFFu + ((x >> 16) & 1u)) >> 16;
}

// pack 8 floats -> 8 bf16 (RNE) in a uint4
__device__ __forceinline__ uint4v pack_bf8(const float v[8]) {
    u32 h[8];
#pragma unroll
    for (int j = 0; j < 8; ++j) h[j] = bf16_rne(v[j]);
    return (uint4v){ h[0] | (h[1] << 16), h[2] | (h[3] << 16),
                     h[4] | (h[5] << 16), h[6] | (h[7] << 16) };
}

// load 8 consecutive floats, scale, split into hi/lo bf16x8 fragments (for tiny GEMMs)
__device__ __forceinline__ void pack8(const float* p, float scale, short8v& ah, short8v& al) {
    float v[8];
#pragma unroll
    for (int j = 0; j < 8; ++j) v[j] = p[j];
    u32 hu[8], lu[8];
#pragma unroll
    for (int j = 0; j < 8; ++j) {
        float s = v[j] * scale;
        hu[j] = bf16_rne(s);
        float fh = __builtin_bit_cast(float, hu[j] << 16);
        lu[j] = bf16_rne(s - fh);
    }
    uint4v hset = { hu[0] | (hu[1] << 16), hu[2] | (hu[3] << 16),
                    hu[4] | (hu[5] << 16), hu[6] | (hu[7] << 16) };
    uint4v lset = { lu[0] | (lu[1] << 16), lu[2] | (lu[3] << 16),
                    lu[4] | (lu[5] << 16), lu[6] | (lu[7] << 16) };
    ah = __builtin_bit_cast(short8v, hset);
    al = __builtin_bit_cast(short8v, lset);
}

// ---------- dedicated e_h kernel: LDS-staged w1, broadcast reads, vector ld/st ----------
__global__ __launch_bounds__(256) void k_eh(
    const float* __restrict__ ea, const float* __restrict__ w1,
    const float* __restrict__ b1, float* __restrict__ e_h) {
    __shared__ float w1s[2048];
    __shared__ float b1s[128];
    int t = threadIdx.x;
#pragma unroll
    for (int i = 0; i < 8; ++i) w1s[i * 256 + t] = w1[i * 256 + t];
    if (t < 128) b1s[t] = b1[t];
    __syncthreads();
    int e = blockIdx.x * 32 + (t & 31);
    int j0 = (t >> 5) * 16;
    const float4* ea4 = (const float4*)ea;
    float4 a0 = ea4[(size_t)e * 4 + 0], a1 = ea4[(size_t)e * 4 + 1];
    float4 a2 = ea4[(size_t)e * 4 + 2], a3 = ea4[(size_t)e * 4 + 3];
    float av[16] = {a0.x, a0.y, a0.z, a0.w, a1.x, a1.y, a1.z, a1.w,
                    a2.x, a2.y, a2.z, a2.w, a3.x, a3.y, a3.z, a3.w};
    float res[16];
#pragma unroll
    for (int jj = 0; jj < 16; ++jj) {
        int j = j0 + jj;
        float s = b1s[j];
#pragma unroll
        for (int c = 0; c < 16; ++c) s += av[c] * w1s[j * 16 + c];
        res[jj] = fmaxf(s, 0.f);
    }
    float4* op = (float4*)&e_h[(size_t)e * 128 + j0];
#pragma unroll
    for (int q = 0; q < 4; ++q)
        op[q] = make_float4(res[q * 4], res[q * 4 + 1], res[q * 4 + 2], res[q * 4 + 3]);
}

// ---------- fused setup: lin0 + wprep + gstart + degi-zero ----------
#define SETUP_LIN0 (NN * 64)
#define SETUP_W2   (64 * SK)
#define SETUP_MW   8192
#define SETUP_GB   24576
#define SETUP_G    (NGB + 1)
#define SETUP_TOTAL (SETUP_LIN0 + SETUP_W2 + SETUP_MW + SETUP_GB + SETUP_G + NN)
__global__ void k_setup(const float* __restrict__ x, const float* __restrict__ lin0_w,
                        const float* __restrict__ lin0_b,
                        const float* __restrict__ nn_w2, const float* __restrict__ conv_root,
                        const float* __restrict__ nn_b2, const float* __restrict__ gw_ih,
                        const float* __restrict__ gw_hh, const int* __restrict__ batch,
                        float* __restrict__ out,
                        u16* __restrict__ Whi, u16* __restrict__ Wlo,
                        u16* __restrict__ Bmh, u16* __restrict__ Bml,
                        u16* __restrict__ Bih_h, u16* __restrict__ Bih_l,
                        u16* __restrict__ Bhh_h, u16* __restrict__ Bhh_l,
                        int* __restrict__ gstart, int* __restrict__ degi) {
    int idx = blockIdx.x * 256 + threadIdx.x;
    if (idx < SETUP_LIN0) {
        int n = idx >> 6, o = idx & 63;
        float s = lin0_b[o];
#pragma unroll
        for (int c = 0; c < 21; ++c) s += x[n * 21 + c] * lin0_w[o * 21 + c];
        out[idx] = fmaxf(s, 0.f);
        return;
    }
    idx -= SETUP_LIN0;
    if (idx < SETUP_W2) {
        int o = idx >> 13, kap = idx & 8191;
        int i = kap >> 7, k = kap & 127;
        float v = nn_w2[(size_t)((i << 6) + o) * 128 + k];
        u32 h = bf16_rne(v);
        float fh = __builtin_bit_cast(float, h << 16);
        u32 l = bf16_rne(v - fh);
        int pos = ((kap >> 3) * 64 + o) * 8 + (kap & 7);
        Whi[pos] = (u16)h; Wlo[pos] = (u16)l;
        return;
    }
    idx -= SETUP_W2;
    if (idx < SETUP_MW) {
        int k = idx >> 6, o = idx & 63;
        float v = (k < 64) ? nn_b2[k * 64 + o] : conv_root[(k - 64) * 64 + o];
        u32 h = bf16_rne(v);
        float fh = __builtin_bit_cast(float, h << 16);
        u32 l = bf16_rne(v - fh);
        int pos = ((k >> 3) * 64 + o) * 8 + (k & 7);
        Bmh[pos] = (u16)h; Bml[pos] = (u16)l;
        return;
    }
    idx -= SETUP_MW;
    if (idx < SETUP_GB) {
        int half = idx >= 12288;
        int i2 = idx - half * 12288;
        int o = i2 % 192, k = i2 / 192;
        float v = half ? gw_hh[o * 64 + k] : gw_ih[o * 64 + k];
        u32 h = bf16_rne(v);
        float fh = __builtin_bit_cast(float, h << 16);
        u32 l = bf16_rne(v - fh);
        int pos = ((k >> 3) * 192 + o) * 8 + (k & 7);
        if (half) { Bhh_h[pos] = (u16)h; Bhh_l[pos] = (u16)l; }
        else      { Bih_h[pos] = (u16)h; Bih_l[pos] = (u16)l; }
        return;
    }
    idx -= SETUP_GB;
    if (idx < SETUP_G) {
        int g = idx;
        int lo = 0, hi = NN;
        while (lo < hi) { int mid = (lo + hi) >> 1; if (batch[mid] < g) lo = mid + 1; else hi = mid; }
        gstart[g] = lo;
        return;
    }
    idx -= SETUP_G;
    if (idx < NN) degi[idx] = 0;
}

__global__ void k_deg(const int* __restrict__ dst, int* __restrict__ degi) {
    int e = blockIdx.x * blockDim.x + threadIdx.x;
    if (e < NE) atomicAdd(&degi[dst[e]], 1);
}

// single-block scan, sequential 8-per-thread chunks + one LDS log-scan
__global__ __launch_bounds__(1024) void k_scan(
    const int* __restrict__ degi, int* __restrict__ rowptr,
    int* __restrict__ cursor, float* __restrict__ degf) {
    __shared__ int tsum[1024];
    int t = threadIdx.x;
    int base = t * 8;
    int v[8];
    int s = 0;
#pragma unroll
    for (int j = 0; j < 8; ++j) {
        int i = base + j;
        v[j] = (i < NN) ? degi[i] : 0;
        s += v[j];
    }
    tsum[t] = s;
    __syncthreads();
    for (int off = 1; off < 1024; off <<= 1) {
        int add = (t >= off) ? tsum[t - off] : 0;
        __syncthreads();
        tsum[t] += add;
        __syncthreads();
    }
    int exc = (t == 0) ? 0 : tsum[t - 1];
#pragma unroll
    for (int j = 0; j < 8; ++j) {
        int i = base + j;
        if (i < NN) {
            rowptr[i] = exc; cursor[i] = exc;
            degf[i] = (float)(v[j] > 1 ? v[j] : 1);
            exc += v[j];
        }
    }
    if (t == 1023) rowptr[NN] = tsum[1023];
}

__global__ void k_fill(const int* __restrict__ dst, int* __restrict__ cursor,
                       int* __restrict__ elist) {
    int e = blockIdx.x * blockDim.x + threadIdx.x;
    if (e < NE) { int p = atomicAdd(&cursor[dst[e]], 1); elist[p] = e; }
}

// ---------- NNConv: S build (bf16 S) ----------
__global__ __launch_bounds__(256) void k_sbuild(
    const float* __restrict__ out, const float* __restrict__ e_h,
    const int* __restrict__ src, const int* __restrict__ rowptr,
    const int* __restrict__ elist, u16* __restrict__ S_bf,
    float* __restrict__ Osum, int base) {
    int t = threadIdx.x;
    int n = base + blockIdx.x;
    int ig = t >> 4;
    int k8 = t & 15;
    int lane = t & 63;
    float acc[4][8];
#pragma unroll
    for (int j = 0; j < 4; ++j)
#pragma unroll
        for (int c = 0; c < 8; ++c) acc[j][c] = 0.f;
    float osum = 0.f;
    int r0 = rowptr[n], r1 = rowptr[n + 1];
    const float4* out4 = (const float4*)out;
    const float4* eh4p = (const float4*)e_h;
    for (int idx = r0; idx < r1; ++idx) {
        int e = elist[idx];
        int sn = src[e];
        float4 e0 = eh4p[(size_t)e * 32 + k8 * 2];
        float4 e1 = eh4p[(size_t)e * 32 + k8 * 2 + 1];
        float ehv[8] = {e0.x, e0.y, e0.z, e0.w, e1.x, e1.y, e1.z, e1.w};
        float4 f = out4[sn * 16 + ig];
        float fv[4] = {f.x, f.y, f.z, f.w};
#pragma unroll
        for (int j = 0; j < 4; ++j)
#pragma unroll
            for (int c = 0; c < 8; ++c) acc[j][c] += fv[j] * ehv[c];
        if (t < 64) osum += out[(size_t)sn * 64 + lane];
    }
    uint4v* S4 = (uint4v*)S_bf;
    size_t rb = (size_t)blockIdx.x * (SK / 8);
#pragma unroll
    for (int j = 0; j < 4; ++j)
        S4[rb + (size_t)(ig * 4 + j) * 16 + k8] = pack_bf8(acc[j]);
    if (t < 64) Osum[(size_t)n * 64 + lane] = osum;
}

// ---------- NNConv: MFMA GEMM. 1 wave/block, M=32/wave, inline A loads, bf16 P ----------
__global__ __launch_bounds__(64) void k_gemm(
    const u16* __restrict__ S_bf, const u16* __restrict__ Whi,
    const u16* __restrict__ Wlo, u16* __restrict__ P, int base) {
    int lane = threadIdx.x;
    int lrow = lane & 15, lkg = lane >> 4;
    int m0 = blockIdx.x * 32;
    int ks = blockIdx.y;
    int kbase = ks * (SK / KSPLIT);         // 512 kappa per split
    float4v acc[2][4];
#pragma unroll
    for (int ms = 0; ms < 2; ++ms)
#pragma unroll
        for (int nt = 0; nt < 4; ++nt) acc[ms][nt] = (float4v){0.f, 0.f, 0.f, 0.f};
    const short8v* bhv = (const short8v*)Whi;
    const short8v* blv = (const short8v*)Wlo;
    const u16* ar0 = S_bf + (size_t)(m0 + lrow) * SK + kbase + lkg * 8;
    const u16* ar1 = ar0 + (size_t)16 * SK;
    int kc0 = (kbase >> 3) + lkg;           // kchunk index (8 kappa per chunk)

#pragma unroll 4
    for (int kk = 0; kk < 16; ++kk) {       // 16 iterations, K=32 each
        short8v ah0 = *(const short8v*)(ar0 + kk * 32);
        short8v ah1 = *(const short8v*)(ar1 + kk * 32);
        int bo = (kc0 + kk * 4) * 64 + lrow;
        short8v bh[4], bl[4];
#pragma unroll
        for (int nt = 0; nt < 4; ++nt) { bh[nt] = bhv[bo + nt * 16]; bl[nt] = blv[bo + nt * 16]; }
#pragma unroll
        for (int nt = 0; nt < 4; ++nt) {
            acc[0][nt] = __builtin_amdgcn_mfma_f32_16x16x32_bf16(ah0, bh[nt], acc[0][nt], 0, 0, 0);
            acc[0][nt] = __builtin_amdgcn_mfma_f32_16x16x32_bf16(ah0, bl[nt], acc[0][nt], 0, 0, 0);
            acc[1][nt] = __builtin_amdgcn_mfma_f32_16x16x32_bf16(ah1, bh[nt], acc[1][nt], 0, 0, 0);
            acc[1][nt] = __builtin_amdgcn_mfma_f32_16x16x32_bf16(ah1, bl[nt], acc[1][nt], 0, 0, 0);
        }
    }
    int gbase = base + m0;
#pragma unroll
    for (int ms = 0; ms < 2; ++ms)
#pragma unroll
        for (int nt = 0; nt < 4; ++nt)
#pragma unroll
            for (int jj = 0; jj < 4; ++jj) {
                int row = ms * 16 + lkg * 4 + jj;   // C/D: row=(lane>>4)*4+reg  [m89 verified]
                int o = nt * 16 + lrow;             //      col=lane&15
                P[((size_t)ks * NN + gbase + row) * 64 + o] = (u16)bf16_rne(acc[ms][nt][jj]);
            }
}

// ---------- fused node update: psum(bf16 P) + mrelu(MFMA) + GRU gates(MFMA) ----------
__global__ __launch_bounds__(64) void k_node(
    float* __restrict__ out, const u16* __restrict__ P,
    const float* __restrict__ Osum, const float* __restrict__ degf,
    const u16* __restrict__ Bmh, const u16* __restrict__ Bml,
    const u16* __restrict__ Bih_h, const u16* __restrict__ Bih_l,
    const u16* __restrict__ Bhh_h, const u16* __restrict__ Bhh_l,
    const float* __restrict__ conv_bias,
    const float* __restrict__ gb_ih, const float* __restrict__ gb_hh) {
    __shared__ float lds[16][68];     // psum, then M (padded stride 68)
    int lane = threadIdx.x;
    int lrow = lane & 15, lkg = lane >> 4;
    int n0 = blockIdx.x * 16;
    int arow = n0 + lrow;

    // phase 1: Psum[arow][lkg*16 .. +15] = sum over KSPLIT bf16 planes
    {
        float ps[16];
#pragma unroll
        for (int c = 0; c < 16; ++c) ps[c] = 0.f;
        for (int p = 0; p < KSPLIT; ++p) {
            const uint4v* Pp = (const uint4v*)(P + (size_t)p * (NN * 64) + (size_t)arow * 64 + lkg * 16);
            uint4v v0 = Pp[0], v1 = Pp[1];
            u32 wv[8] = {v0.x, v0.y, v0.z, v0.w, v1.x, v1.y, v1.z, v1.w};
#pragma unroll
            for (int q = 0; q < 8; ++q) {
                ps[q * 2]     += __builtin_bit_cast(float, wv[q] << 16);
                ps[q * 2 + 1] += __builtin_bit_cast(float, wv[q] & 0xFFFF0000u);
            }
        }
#pragma unroll
        for (int c = 0; c < 16; ++c) lds[lrow][lkg * 16 + c] = ps[c];
    }
    __syncthreads();

    // phase 2: mrelu MFMA (A rows: Osum/deg then out; B: nn_b2 then conv_root)
    float invd = 1.f / degf[arow];
    float4v acc[4];
#pragma unroll
    for (int nt = 0; nt < 4; ++nt) acc[nt] = (float4v){0.f, 0.f, 0.f, 0.f};
    const short8v* bhv = (const short8v*)Bmh;
    const short8v* blv = (const short8v*)Bml;
#pragma unroll
    for (int s = 0; s < 4; ++s) {
        short8v ah, al;
        if (s < 2) pack8(&Osum[(size_t)arow * 64 + s * 32 + lkg * 8], invd, ah, al);
        else       pack8(&out[(size_t)arow * 64 + (s - 2) * 32 + lkg * 8], 1.f, ah, al);
        int kc = s * 4 + lkg;
#pragma unroll
        for (int nt = 0; nt < 4; ++nt) {
            short8v bh = bhv[kc * 64 + nt * 16 + lrow];
            short8v bl = blv[kc * 64 + nt * 16 + lrow];
            acc[nt] = __builtin_amdgcn_mfma_f32_16x16x32_bf16(ah, bh, acc[nt], 0, 0, 0);
            acc[nt] = __builtin_amdgcn_mfma_f32_16x16x32_bf16(al, bh, acc[nt], 0, 0, 0);
            acc[nt] = __builtin_amdgcn_mfma_f32_16x16x32_bf16(ah, bl, acc[nt], 0, 0, 0);
        }
    }
    float invd2[4];
#pragma unroll
    for (int jj = 0; jj < 4; ++jj) invd2[jj] = 1.f / degf[n0 + lkg * 4 + jj];
    float mval[4][4];
#pragma unroll
    for (int nt = 0; nt < 4; ++nt) {
        int o = nt * 16 + lrow;
        float cb = conv_bias[o];
#pragma unroll
        for (int jj = 0; jj < 4; ++jj)
            mval[nt][jj] = fmaxf(acc[nt][jj] + lds[lkg * 4 + jj][o] * invd2[jj] + cb, 0.f);
    }
    __syncthreads();   // all psum reads done
#pragma unroll
    for (int nt = 0; nt < 4; ++nt)
#pragma unroll
        for (int jj = 0; jj < 4; ++jj)
            lds[lkg * 4 + jj][nt * 16 + lrow] = mval[nt][jj];
    __syncthreads();   // M ready in LDS

    // phase 3: GRU gates MFMA
    float4v ai[12], ah_[12];
#pragma unroll
    for (int nt = 0; nt < 12; ++nt) { ai[nt] = (float4v){0.f, 0.f, 0.f, 0.f}; ah_[nt] = (float4v){0.f, 0.f, 0.f, 0.f}; }
    const short8v* bih_h = (const short8v*)Bih_h;
    const short8v* bih_l = (const short8v*)Bih_l;
    const short8v* bhh_h = (const short8v*)Bhh_h;
    const short8v* bhh_l = (const short8v*)Bhh_l;
#pragma unroll
    for (int s = 0; s < 2; ++s) {
        short8v mh, ml, hh, hl;
        pack8(&lds[lrow][s * 32 + lkg * 8], 1.f, mh, ml);
        pack8(&out[(size_t)arow * 64 + s * 32 + lkg * 8], 1.f, hh, hl);
        int kc = s * 4 + lkg;
#pragma unroll
        for (int nt = 0; nt < 12; ++nt) {
            int bo = kc * 192 + nt * 16 + lrow;
            short8v b1 = bih_h[bo], b2 = bih_l[bo];
            ai[nt] = __builtin_amdgcn_mfma_f32_16x16x32_bf16(mh, b1, ai[nt], 0, 0, 0);
            ai[nt] = __builtin_amdgcn_mfma_f32_16x16x32_bf16(ml, b1, ai[nt], 0, 0, 0);
            ai[nt] = __builtin_amdgcn_mfma_f32_16x16x32_bf16(mh, b2, ai[nt], 0, 0, 0);
            short8v b3 = bhh_h[bo], b4 = bhh_l[bo];
            ah_[nt] = __builtin_amdgcn_mfma_f32_16x16x32_bf16(hh, b3, ah_[nt], 0, 0, 0);
            ah_[nt] = __builtin_amdgcn_mfma_f32_16x16x32_bf16(hl, b3, ah_[nt], 0, 0, 0);
            ah_[nt] = __builtin_amdgcn_mfma_f32_16x16x32_bf16(hh, b4, ah_[nt], 0, 0, 0);
        }
    }
#pragma unroll
    for (int nt = 0; nt < 4; ++nt) {
        int o = nt * 16 + lrow;
        float bi0 = gb_ih[o], bi1 = gb_ih[64 + o], bi2 = gb_ih[128 + o];
        float bh0 = gb_hh[o], bh1 = gb_hh[64 + o], bh2 = gb_hh[128 + o];
#pragma unroll
        for (int jj = 0; jj < 4; ++jj) {
            int row = n0 + lkg * 4 + jj;
            float ir = ai[nt][jj] + bi0,  hr = ah_[nt][jj] + bh0;
            float iz = ai[nt + 4][jj] + bi1, hz = ah_[nt + 4][jj] + bh1;
            float in_ = ai[nt + 8][jj] + bi2, hn = ah_[nt + 8][jj] + bh2;
            float r = sigmoidf_(ir + hr);
            float z = sigmoidf_(iz + hz);
            float nv = tanhf(in_ + r * hn);
            float ho = out[(size_t)row * 64 + o];
            out[(size_t)row * 64 + o] = (1.f - z) * nv + z * ho;
        }
    }
}

// ---------- fused Set2Set: 3x(LSTM+attention) + final linear, one block per graph ----------
__global__ __launch_bounds__(256) void k_s2s(
    const float* __restrict__ out, const int* __restrict__ gstart,
    const float* __restrict__ lw_ih, const float* __restrict__ lw_hh,
    const float* __restrict__ lb_ih, const float* __restrict__ lb_hh,
    const float* __restrict__ lin1_w, const float* __restrict__ lin1_b,
    const float* __restrict__ lin2_w, const float* __restrict__ lin2_b,
    float* __restrict__ yout) {
    __shared__ float qs[128], hsL[64], csL[64], gates[256];
    __shared__ float pv[384];
    __shared__ float red[4][64];
    __shared__ float sswv[4], mmaxw[4];
    int g = blockIdx.x, t = threadIdx.x, wv = t >> 6, lane = t & 63;
    int s0 = gstart[g], s1 = gstart[g + 1];
    if (t < 128) qs[t] = 0.f;
    if (t < 64) { hsL[t] = 0.f; csL[t] = 0.f; }
    __syncthreads();
    for (int st = 0; st < 3; ++st) {
        float s = lb_ih[t] + lb_hh[t];
        const float4* wi = (const float4*)&lw_ih[t * 128];
#pragma unroll
        for (int i = 0; i < 32; ++i) {
            float4 a = wi[i];
            s += qs[i * 4] * a.x + qs[i * 4 + 1] * a.y + qs[i * 4 + 2] * a.z + qs[i * 4 + 3] * a.w;
        }
        const float4* wh = (const float4*)&lw_hh[t * 64];
#pragma unroll
        for (int i = 0; i < 16; ++i) {
            float4 a = wh[i];
            s += hsL[i * 4] * a.x + hsL[i * 4 + 1] * a.y + hsL[i * 4 + 2] * a.z + hsL[i * 4 + 3] * a.w;
        }
        gates[t] = s;
        __syncthreads();
        if (t < 64) {
            float ig = sigmoidf_(gates[t]);
            float fg = sigmoidf_(gates[64 + t]);
            float gg = tanhf(gates[128 + t]);
            float og = sigmoidf_(gates[192 + t]);
            float c = fg * csL[t] + ig * gg;
            csL[t] = c;
            hsL[t] = og * tanhf(c);
        }
        __syncthreads();
        float wmax = -1e30f;
        for (int i = s0 + wv; i < s1; i += 4) {
            float p = out[(size_t)i * 64 + lane] * hsL[lane];
#pragma unroll
            for (int off = 32; off >= 1; off >>= 1) p += __shfl_xor(p, off);
            if (lane == 0) pv[i - s0] = p;
            wmax = fmaxf(wmax, p);
        }
        if (lane == 0) mmaxw[wv] = wmax;
        __syncthreads();
        float mmax = fmaxf(fmaxf(mmaxw[0], mmaxw[1]), fmaxf(mmaxw[2], mmaxw[3]));
        float ssum = 0.f, racc = 0.f;
        for (int i = s0 + wv; i < s1; i += 4) {
            float w = expf(pv[i - s0] - mmax);
            ssum += w;
            racc += w * out[(size_t)i * 64 + lane];
        }
        red[wv][lane] = racc;
        if (lane == 0) sswv[wv] = ssum;
        __syncthreads();
        if (t < 64) {
            float rt = red[0][t] + red[1][t] + red[2][t] + red[3][t];
            float stot = sswv[0] + sswv[1] + sswv[2] + sswv[3];
            qs[t] = hsL[t];
            qs[64 + t] = (s1 > s0) ? rt / stot : 0.f;
        }
        __syncthreads();
    }
    if (t < 64) {
        float s = lin1_b[t];
        const float4* w1 = (const float4*)&lin1_w[t * 128];
#pragma unroll
        for (int i = 0; i < 32; ++i) {
            float4 a = w1[i];
            s += qs[i * 4] * a.x + qs[i * 4 + 1] * a.y + qs[i * 4 + 2] * a.z + qs[i * 4 + 3] * a.w;
        }
        s = fmaxf(s, 0.f) * lin2_w[t];
#pragma unroll
        for (int off = 32; off >= 1; off >>= 1) s += __shfl_xor(s, off);
        if (t == 0) yout[g] = s + lin2_b[0];
    }
}

extern "C" void kernel_launch(void* const* d_in, const int* in_sizes, int n_in,
                              void* d_out, int out_size, void* d_ws, size_t ws_size,
                              hipStream_t stream) {
    (void)in_sizes; (void)n_in; (void)out_size;
    const float* x        = (const float*)d_in[0];
    const float* eattr    = (const float*)d_in[1];
    const int*   ei       = (const int*)d_in[2];
    const int*   batch    = (const int*)d_in[3];
    const float* lin0_w   = (const float*)d_in[4];
    const float* lin0_b   = (const float*)d_in[5];
    const float* nn_w1    = (const float*)d_in[6];
    const float* nn_b1    = (const float*)d_in[7];
    const float* nn_w2    = (const float*)d_in[8];
    const float* nn_b2    = (const float*)d_in[9];
    const float* conv_root= (const float*)d_in[10];
    const float* conv_bias= (const float*)d_in[11];
    const float* gw_ih    = (const float*)d_in[12];
    const float* gw_hh    = (const float*)d_in[13];
    const float* gb_ih    = (const float*)d_in[14];
    const float* gb_hh    = (const float*)d_in[15];
    const float* lw_ih    = (const float*)d_in[16];
    const float* lw_hh    = (const float*)d_in[17];
    const float* lb_ih    = (const float*)d_in[18];
    const float* lb_hh    = (const float*)d_in[19];
    const float* lin1_w   = (const float*)d_in[20];
    const float* lin1_b   = (const float*)d_in[21];
    const float* lin2_w   = (const float*)d_in[22];
    const float* lin2_b   = (const float*)d_in[23];
    const int* src = ei;
    const int* dst = ei + NE;

    char* w = (char*)d_ws;
    auto alloc = [&](size_t bytes) { char* p = w; w += (bytes + 255) & ~(size_t)255; return p; };
    float* out    = (float*)alloc((size_t)NN * 64 * 4);
    float* e_h    = (float*)alloc((size_t)NE * 128 * 4);
    u16*   Whi    = (u16*)alloc((size_t)64 * SK * 2);
    u16*   Wlo    = (u16*)alloc((size_t)64 * SK * 2);
    u16*   P      = (u16*)alloc((size_t)KSPLIT * NN * 64 * 2);
    float* Osum   = (float*)alloc((size_t)NN * 64 * 4);
    u16*   Bmh    = (u16*)alloc((size_t)8192 * 2);
    u16*   Bml    = (u16*)alloc((size_t)8192 * 2);
    u16*   Bih_h  = (u16*)alloc((size_t)12288 * 2);
    u16*   Bih_l  = (u16*)alloc((size_t)12288 * 2);
    u16*   Bhh_h  = (u16*)alloc((size_t)12288 * 2);
    u16*   Bhh_l  = (u16*)alloc((size_t)12288 * 2);
    float* degf   = (float*)alloc((size_t)NN * 4);
    int*   degi   = (int*)alloc((size_t)NN * 4);
    int*   rowptr = (int*)alloc((size_t)(NN + 1) * 4);
    int*   cursor = (int*)alloc((size_t)(NN + 1) * 4);
    int*   elist  = (int*)alloc((size_t)NE * 4);
    int*   gstart = (int*)alloc((size_t)(NGB + 1) * 4);
    size_t used = (size_t)(w - (char*)d_ws);
    size_t avail = ws_size > used ? ws_size - used : 0;
    size_t maxrows = avail / ((size_t)SK * 2);      // bf16 S: 16 KB per row
    int chunkN = maxrows > (size_t)NN ? NN : (int)maxrows;
    chunkN = (chunkN / 64) * 64;
    if (chunkN < 64) chunkN = 64;
    u16* S_bf = (u16*)w;

    k_setup<<<(SETUP_TOTAL + 255) / 256, 256, 0, stream>>>(
        x, lin0_w, lin0_b, nn_w2, conv_root, nn_b2,
        gw_ih, gw_hh, batch, out, Whi, Wlo, Bmh, Bml,
        Bih_h, Bih_l, Bhh_h, Bhh_l, gstart, degi);
    k_eh<<<NE / 32, 256, 0, stream>>>(eattr, nn_w1, nn_b1, e_h);
    k_deg<<<(NE + 255) / 256, 256, 0, stream>>>(dst, degi);
    k_scan<<<1, 1024, 0, stream>>>(degi, rowptr, cursor, degf);
    k_fill<<<(NE + 255) / 256, 256, 0, stream>>>(dst, cursor, elist);

    for (int it = 0; it < 3; ++it) {
        for (int cb = 0; cb < NN; cb += chunkN) {
            int cn = (NN - cb) < chunkN ? (NN - cb) : chunkN;
            k_sbuild<<<cn, 256, 0, stream>>>(out, e_h, src, rowptr, elist, S_bf, Osum, cb);
            k_gemm<<<dim3(cn / 32, KSPLIT), 64, 0, stream>>>(S_bf, Whi, Wlo, P, cb);
        }
        k_node<<<NN / 16, 64, 0, stream>>>(out, P, Osum, degf, Bmh, Bml,
                                           Bih_h, Bih_l, Bhh_h, Bhh_l,
                                           conv_bias, gb_ih, gb_hh);
    }

    k_s2s<<<NGB, 256, 0, stream>>>(out, gstart, lw_ih, lw_hh, lb_ih, lb_hh,
                                   lin1_w, lin1_b, lin2_w, lin2_b, (float*)d_out);
}